// Round 1
// baseline (1205.882 us; speedup 1.0000x reference)
//
#include <hip/hip_runtime.h>

#define NSAMP 2097152
#define DIM 64
#define NCLS 10

// ---------------------------------------------------------------------------
// Kernel 1 (tiny): muP[c][j] = sum_i mu[c][i] * P[i][j]
//                  b[c]      = -0.5 * sum_j muP[c][j] * mu[c][j]
//                  ws layout: [0, 640) = muP, [640, 650) = b_c, [650] = alpha
// ---------------------------------------------------------------------------
__global__ __launch_bounds__(256) void precomp_kernel(
    const float* __restrict__ mu, const float* __restrict__ P,
    const float* __restrict__ alpha, float* __restrict__ ws)
{
    __shared__ float muP_s[NCLS * DIM];
    const int t = threadIdx.x;
    for (int idx = t; idx < NCLS * DIM; idx += 256) {
        const int c = idx >> 6;
        const int j = idx & 63;
        float s = 0.f;
        #pragma unroll
        for (int i = 0; i < DIM; ++i) s += mu[c * DIM + i] * P[i * DIM + j];
        muP_s[idx] = s;
        ws[idx] = s;
    }
    __syncthreads();
    if (t < NCLS) {
        float q = 0.f;
        #pragma unroll
        for (int j = 0; j < DIM; ++j) q += muP_s[t * DIM + j] * mu[t * DIM + j];
        ws[NCLS * DIM + t] = -0.5f * q;
    }
    if (t == 0) ws[NCLS * DIM + NCLS] = alpha[0];
}

// ---------------------------------------------------------------------------
// Main kernel: one thread = one sample.
//   qf   = f P f^T      (64 rows; P row via uniform s_load, f[j] in VGPRs,
//                        f[i] broadcast multiplier via private LDS slot)
//   best = max_c (f . muP_c + b_c)
//   out  = alpha * (-0.5*qf + best)
// LDS: 16 floats/thread staged in 4 phases -> 16 KB/block (not occupancy
// binding; VGPR (~80, f[64]) binds at ~6 waves/SIMD).
// ---------------------------------------------------------------------------
__global__ __launch_bounds__(256) void mahal_kernel(
    const float* __restrict__ feat, const float* __restrict__ P,
    const float* __restrict__ ws, float* __restrict__ out)
{
    const int tid = threadIdx.x;
    const long long n = (long long)blockIdx.x * 256 + tid;

    __shared__ float flds[16 * 256];  // [i2][tid], bank = tid%32 -> conflict-free

    // Load this sample's feature row (64 floats, 4x dwordx4-friendly).
    float f[DIM];
    const float4* fp = (const float4*)(feat + n * DIM);
    #pragma unroll
    for (int k = 0; k < 16; ++k) {
        const float4 v = fp[k];
        f[4 * k + 0] = v.x; f[4 * k + 1] = v.y;
        f[4 * k + 2] = v.z; f[4 * k + 3] = v.w;
    }

    float qf = 0.f;
    #pragma unroll
    for (int p = 0; p < 4; ++p) {
        // Stage f[16p .. 16p+15] into private LDS slots (same-thread RAW, no
        // barrier needed).
        #pragma unroll
        for (int u = 0; u < 16; ++u) flds[u * 256 + tid] = f[16 * p + u];

        #pragma unroll 1
        for (int i2 = 0; i2 < 16; ++i2) {
            const int i = 16 * p + i2;
            const float fi = flds[i2 * 256 + tid];
            const float* Pr = P + i * DIM;   // uniform address -> s_load
            float w0 = 0.f, w1 = 0.f, w2 = 0.f, w3 = 0.f;
            #pragma unroll
            for (int j = 0; j < DIM; j += 4) {
                w0 += Pr[j + 0] * f[j + 0];
                w1 += Pr[j + 1] * f[j + 1];
                w2 += Pr[j + 2] * f[j + 2];
                w3 += Pr[j + 3] * f[j + 3];
            }
            qf += ((w0 + w1) + (w2 + w3)) * fi;
        }
    }

    // Cross terms + per-class bias; max over classes.
    float best = -3.4e38f;
    #pragma unroll 1
    for (int c = 0; c < NCLS; ++c) {
        const float* mr = ws + c * DIM;      // uniform -> s_load
        float s0 = 0.f, s1 = 0.f, s2 = 0.f, s3 = 0.f;
        #pragma unroll
        for (int j = 0; j < DIM; j += 4) {
            s0 += mr[j + 0] * f[j + 0];
            s1 += mr[j + 1] * f[j + 1];
            s2 += mr[j + 2] * f[j + 2];
            s3 += mr[j + 3] * f[j + 3];
        }
        const float sc = ((s0 + s1) + (s2 + s3)) + ws[NCLS * DIM + c];
        best = fmaxf(best, sc);
    }

    const float a = ws[NCLS * DIM + NCLS];
    out[n] = a * (-0.5f * qf + best);
}

extern "C" void kernel_launch(void* const* d_in, const int* in_sizes, int n_in,
                              void* d_out, int out_size, void* d_ws, size_t ws_size,
                              hipStream_t stream) {
    const float* features = (const float*)d_in[0];
    const float* mu       = (const float*)d_in[1];
    const float* P        = (const float*)d_in[2];
    const float* alpha    = (const float*)d_in[3];
    float* out = (float*)d_out;
    float* ws  = (float*)d_ws;

    precomp_kernel<<<1, 256, 0, stream>>>(mu, P, alpha, ws);
    mahal_kernel<<<NSAMP / 256, 256, 0, stream>>>(features, P, ws, out);
}

// Round 2
// 699.841 us; speedup vs baseline: 1.7231x; 1.7231x over previous
//
#include <hip/hip_runtime.h>

#define NSAMP 2097152
#define DIM 64
#define NCLS 10
#define NT 5              // 5 column-tiles of 16: cols 0..63 = P, 64..79 = classes (padded)
#define TILES_PER_WAVE 8
#define WPB 4             // waves per block
#define SPB (WPB * 16 * TILES_PER_WAVE)  // 512 samples per block

typedef __attribute__((ext_vector_type(8))) short short8;
typedef __attribute__((ext_vector_type(4))) float floatx4;

// ---- bf16 helpers (RNE) ---------------------------------------------------
__device__ __forceinline__ unsigned bf16_rne_bits(float a) {
    unsigned u = __float_as_uint(a);
    return u + 0x7FFFu + ((u >> 16) & 1u);
}
__device__ __forceinline__ short f2bf(float a) { return (short)(bf16_rne_bits(a) >> 16); }
__device__ __forceinline__ float bf_hi_f(float a) {
    return __uint_as_float(bf16_rne_bits(a) & 0xFFFF0000u);
}
__device__ __forceinline__ float bf2f(short s) {
    return __uint_as_float(((unsigned)(unsigned short)s) << 16);
}
__device__ __forceinline__ unsigned pk2(float a, float b) {
    return (bf16_rne_bits(a) >> 16) | (bf16_rne_bits(b) & 0xFFFF0000u);
}

union S8 { unsigned u[4]; short8 v; };

// ---------------------------------------------------------------------------
// Precompute into ws:
//   Mt_hi[80][64] bf16  (Mt[n][k]: n<64 -> P[k][n]; 64<=n<74 -> muP[n-64][k]; else 0)
//   Mt_lo[80][64] bf16  (residual after hi)
//   b[16] fp32 (b_c = -0.5 mu_c P mu_c^T for c<10, else -1e30), then alpha
// ---------------------------------------------------------------------------
__global__ __launch_bounds__(256) void precomp_kernel(
    const float* __restrict__ mu, const float* __restrict__ P,
    const float* __restrict__ alpha, void* __restrict__ ws)
{
    __shared__ float muP_s[NCLS * DIM];
    __shared__ float b_s[NCLS];
    short* mt_hi = (short*)ws;
    short* mt_lo = mt_hi + 80 * 64;
    float* bws   = (float*)(mt_hi + 2 * 80 * 64);

    const int t = threadIdx.x;
    for (int idx = t; idx < NCLS * DIM; idx += 256) {
        const int c = idx >> 6, j = idx & 63;
        float s = 0.f;
        #pragma unroll
        for (int i = 0; i < DIM; ++i) s += mu[c * DIM + i] * P[i * DIM + j];
        muP_s[idx] = s;
    }
    __syncthreads();
    if (t < NCLS) {
        float q = 0.f;
        #pragma unroll
        for (int j = 0; j < DIM; ++j) q += muP_s[t * DIM + j] * mu[t * DIM + j];
        b_s[t] = -0.5f * q;
    }
    __syncthreads();
    for (int idx = t; idx < 80 * 64; idx += 256) {
        const int n = idx >> 6, k = idx & 63;
        float v = 0.f;
        if (n < 64)       v = P[k * DIM + n];
        else if (n < 64 + NCLS) v = muP_s[(n - 64) * DIM + k];
        const short hi = f2bf(v);
        mt_hi[idx] = hi;
        mt_lo[idx] = f2bf(v - bf2f(hi));
    }
    if (t < 16) bws[t] = (t < NCLS) ? b_s[t] : -1e30f;
    if (t == 0) bws[16] = alpha[0];
}

// ---------------------------------------------------------------------------
// Main kernel. One wave = one 16-sample M-tile per iteration.
//   G[16][80] = f_tile @ [P | muP^T]  via mfma_f32_16x16x32_bf16, hi/lo split
//   qf[m] = sum_j G[m][j] f[m][j]  (f re-read from LDS in C/D layout)
//   out[m] = alpha * (max_c(G[m][64+c] + b_c) - 0.5 qf[m])
// ---------------------------------------------------------------------------
__global__ __launch_bounds__(256) void mahal_kernel(
    const float* __restrict__ feat, const void* __restrict__ ws,
    float* __restrict__ out)
{
    const short* mt_hi = (const short*)ws;
    const short* mt_lo = mt_hi + 80 * 64;
    const float* bws   = (const float*)(mt_hi + 2 * 80 * 64);

    const int tid  = threadIdx.x;
    const int w    = tid >> 6;
    const int lane = tid & 63;
    const int ln   = lane & 15;   // A: m-row / B: n-col / C: n-col
    const int q    = lane >> 4;   // k-group / C: m-group

    __shared__ float fl[WPB][16 * 68];   // stride 68 -> <=2-way LDS aliasing (free)
    float* flw = &fl[w][0];

    // Load B fragments once per wave: B[k = h*32 + q*8 + j][n = 16t + ln]
    short8 bh[NT][2], bl[NT][2];
    #pragma unroll
    for (int t = 0; t < NT; ++t)
        #pragma unroll
        for (int h = 0; h < 2; ++h) {
            const int off = (16 * t + ln) * 64 + h * 32 + q * 8;
            bh[t][h] = *(const short8*)(mt_hi + off);
            bl[t][h] = *(const short8*)(mt_lo + off);
        }
    const float bc    = bws[ln];    // -1e30 for padded classes
    const float alpha = bws[16];

    const long sbase0 = ((long)blockIdx.x * WPB + w) * (16 * TILES_PER_WAVE);

    #pragma unroll 1
    for (int it = 0; it < TILES_PER_WAVE; ++it) {
        const long sbase = sbase0 + (long)it * 16;

        // A-tile: lane holds f[m=ln][k = q*8+j (+32h)], 16 floats
        const float* fr = feat + (sbase + ln) * DIM + q * 8;
        const float4 t0 = *(const float4*)(fr);
        const float4 t1 = *(const float4*)(fr + 4);
        const float4 t2 = *(const float4*)(fr + 32);
        const float4 t3 = *(const float4*)(fr + 36);

        // Stage f to LDS for the epilogue (read back in C/D layout)
        float* fp = flw + ln * 68 + q * 8;
        *(float4*)(fp)      = t0;
        *(float4*)(fp + 4)  = t1;
        *(float4*)(fp + 32) = t2;
        *(float4*)(fp + 36) = t3;

        // Build hi/lo A fragments
        const float h0[8] = {t0.x, t0.y, t0.z, t0.w, t1.x, t1.y, t1.z, t1.w};
        const float h1[8] = {t2.x, t2.y, t2.z, t2.w, t3.x, t3.y, t3.z, t3.w};
        S8 ah0, ah1, al0, al1;
        #pragma unroll
        for (int i = 0; i < 4; ++i) {
            const float a0 = h0[2 * i], b0 = h0[2 * i + 1];
            const float a1 = h1[2 * i], b1 = h1[2 * i + 1];
            ah0.u[i] = pk2(a0, b0);
            ah1.u[i] = pk2(a1, b1);
            al0.u[i] = pk2(a0 - bf_hi_f(a0), b0 - bf_hi_f(b0));
            al1.u[i] = pk2(a1 - bf_hi_f(a1), b1 - bf_hi_f(b1));
        }
        const short8 A_h[2] = {ah0.v, ah1.v};
        const short8 A_l[2] = {al0.v, al1.v};

        // MFMA: 5 n-tiles x 2 k-halves x 3 split terms
        floatx4 acc[NT];
        #pragma unroll
        for (int t = 0; t < NT; ++t) {
            floatx4 a = {0.f, 0.f, 0.f, 0.f};
            #pragma unroll
            for (int h = 0; h < 2; ++h) {
                a = __builtin_amdgcn_mfma_f32_16x16x32_bf16(A_h[h], bh[t][h], a, 0, 0, 0);
                a = __builtin_amdgcn_mfma_f32_16x16x32_bf16(A_h[h], bl[t][h], a, 0, 0, 0);
                a = __builtin_amdgcn_mfma_f32_16x16x32_bf16(A_l[h], bh[t][h], a, 0, 0, 0);
            }
            acc[t] = a;
        }

        // Epilogue: lane holds D[m = q*4+r][n = 16t+ln]
        float qf[4] = {0.f, 0.f, 0.f, 0.f};
        float sc[4];
        #pragma unroll
        for (int r = 0; r < 4; ++r) {
            const float* frow = flw + (q * 4 + r) * 68;
            #pragma unroll
            for (int t = 0; t < 4; ++t) qf[r] += acc[t][r] * frow[16 * t + ln];
            sc[r] = acc[4][r] + bc;
        }
        #pragma unroll
        for (int d = 1; d < 16; d <<= 1) {
            #pragma unroll
            for (int r = 0; r < 4; ++r) {
                qf[r] += __shfl_xor(qf[r], d);
                sc[r] = fmaxf(sc[r], __shfl_xor(sc[r], d));
            }
        }
        if (ln < 4) {
            const float qv = (ln == 0) ? qf[0] : (ln == 1) ? qf[1] : (ln == 2) ? qf[2] : qf[3];
            const float sv = (ln == 0) ? sc[0] : (ln == 1) ? sc[1] : (ln == 2) ? sc[2] : sc[3];
            out[sbase + q * 4 + ln] = alpha * (sv - 0.5f * qv);
        }
    }
}

extern "C" void kernel_launch(void* const* d_in, const int* in_sizes, int n_in,
                              void* d_out, int out_size, void* d_ws, size_t ws_size,
                              hipStream_t stream) {
    const float* features = (const float*)d_in[0];
    const float* mu       = (const float*)d_in[1];
    const float* P        = (const float*)d_in[2];
    const float* alpha    = (const float*)d_in[3];
    float* out = (float*)d_out;

    precomp_kernel<<<1, 256, 0, stream>>>(mu, P, alpha, d_ws);
    mahal_kernel<<<NSAMP / SPB, 256, 0, stream>>>(features, d_ws, out);
}